// Round 15
// baseline (76.602 us; speedup 1.0000x reference)
//
#include <hip/hip_runtime.h>

// GMLoss: bidirectional chamfer min + Geman-McClure penalty (MU=1).
// srcs, tgts: [B=8, D=3, N=4096] fp32. Output: scalar fp32.
//
// R15 = R14 (74.3us best) with chamfer back on 32x32x16 MFMA. R13's
// 32x32-regression is now understood (cap-128 register squeeze -> scratch
// spill: VGPR=64, WRITE 244MB), NOT the shape itself. At __launch_bounds__
// (256,2) (cap 256) the 32x32 live set (~90: 2 A-frags + 2 floatx16 rmin +
// depth-4 ring + addr) fits with slack. vs R14's 16x16+K-replication:
//   - no K duplication: each 1024B B-tile read exactly once (R14: 2x) ->
//     L1 delivery 268->134MB,
//   - 4x fewer MFMA (1024 true pairs/instr vs 256),
//   - v_min per pair unchanged (the 3.4us VALU floor).
// Validation: chamfer VGPR 90-120, WRITE_SIZE ~KB (no spill).
//
// Kept (absmax 0.0 since R6): K=13 hi/lo pack, plain stores + tiny finish
// (NO fences / hot atomics - R7/R9), XCD swizzle group=blk&15, depth-4 ring.
//   A k: [-2sh(3), -2sl(3), -2sh(3), s2h, s2l, 1, 1, 0,0,0]
//   B k: [ th(3),   th(3),   tl(3),  1, 1, t2h, t2l, 0,0,0]
//   dot = |s|^2+|t|^2-2s.t  (drops sl.tl ~1e-5 << 1.26e-3 threshold).
// 32x32x16 layouts (m74/m101, used in R6-R8 absmax 0.0):
//   A[m=lane&31][k=(lane>>5)*8+j], B same (n=lane&31);
//   D: col=lane&31, row=(reg&3)+8*(reg>>2)+4*(lane>>5).  D = P (no halving).

#define NPTS 4096
#define NB   8

typedef __attribute__((ext_vector_type(8)))  short bf16x8;
typedef __attribute__((ext_vector_type(16))) float floatx16;

// ws layout: Apack[srcs], Apack[tgts], Bpack[srcs], Bpack[tgts], bsum[1024]
#define OFF_APACK_S 0u
#define OFF_APACK_T (1u << 20)
#define OFF_BPACK_S (2u << 20)
#define OFF_BPACK_T (3u << 20)
#define OFF_BSUM    (4u << 20)

union V16 { int4 i; bf16x8 h; };

__device__ __forceinline__ unsigned short f2bf(float f) {
    unsigned u = __float_as_uint(f);
    u += 0x7FFFu + ((u >> 16) & 1u);       // RNE
    return (unsigned short)(u >> 16);
}
__device__ __forceinline__ float bf2f(unsigned short h) {
    return __uint_as_float(((unsigned)h) << 16);
}
__device__ __forceinline__ int pk(unsigned short lo, unsigned short hi) {
    return (int)((unsigned)lo | ((unsigned)hi << 16));
}

// ---------------- Kernel 1: pack A-style + B-style, 1 point/thread --------
__device__ __forceinline__ void pack_point(const float* __restrict__ cloud,
                                           int b, int j, int gid,
                                           char* __restrict__ apack,
                                           char* __restrict__ bpack) {
    const unsigned short ONE = 0x3F80;
    const float* p = cloud + b * 3 * NPTS;
    const float x = p[j], y = p[NPTS + j], z = p[2 * NPTS + j];
    const unsigned short hx = f2bf(x), hy = f2bf(y), hz = f2bf(z);
    const unsigned short lx = f2bf(x - bf2f(hx));
    const unsigned short ly = f2bf(y - bf2f(hy));
    const unsigned short lz = f2bf(z - bf2f(hz));
    const unsigned short a0 = f2bf(-2.0f * bf2f(hx));
    const unsigned short a1 = f2bf(-2.0f * bf2f(hy));
    const unsigned short a2 = f2bf(-2.0f * bf2f(hz));
    const unsigned short m0 = f2bf(-2.0f * (x - bf2f(hx)));
    const unsigned short m1 = f2bf(-2.0f * (y - bf2f(hy)));
    const unsigned short m2 = f2bf(-2.0f * (z - bf2f(hz)));
    const float n2 = fmaf(z, z, fmaf(y, y, x * x));
    const unsigned short n2h = f2bf(n2);
    const unsigned short n2l = f2bf(n2 - bf2f(n2h));

    int4* Ap = (int4*)(apack + (size_t)gid * 32);
    Ap[0] = make_int4(pk(a0, a1), pk(a2, m0), pk(m1, m2), pk(a0, a1));
    Ap[1] = make_int4(pk(a2, n2h), pk(n2l, ONE), pk(ONE, 0), 0);

    int4* Bp = (int4*)(bpack + (size_t)gid * 32);
    Bp[0] = make_int4(pk(hx, hy), pk(hz, hx), pk(hy, hz), pk(lx, ly));
    Bp[1] = make_int4(pk(lz, ONE), pk(ONE, n2h), pk(n2l, 0), 0);
}

__global__ __launch_bounds__(256)
void transform_kernel(const float* __restrict__ srcs,
                      const float* __restrict__ tgts,
                      char* __restrict__ ws) {
    const int gid = blockIdx.x * 256 + threadIdx.x;   // 0..65535
    const int dir = gid >> 15;
    const int rem = gid & 32767;                      // b*4096 + j
    const int b = rem >> 12, j = rem & 4095;
    if (dir == 0)
        pack_point(srcs, b, j, rem, ws + OFF_APACK_S, ws + OFF_BPACK_S);
    else
        pack_point(tgts, b, j, rem, ws + OFF_APACK_T, ws + OFF_BPACK_T);
}

// ---------------- Kernel 2: row-min MFMA chamfer (32x32x16, 64 rows) ------
__global__ __launch_bounds__(256, 2)
void chamfer_kernel(char* __restrict__ ws) {
    const int blk    = blockIdx.x;        // 0..1023
    const int group  = blk & 15;          // XCD-aware swizzle
    const int dir    = group >> 3;
    const int b      = group & 7;
    const int stripe = blk >> 4;          // 0..63, 64 query rows each
    const int tid    = threadIdx.x;
    const int wave   = tid >> 6;          // 0..3
    const int lane   = tid & 63;
    const int l31    = lane & 31;
    const int half   = lane >> 5;         // k-half = half*16 bytes

    const char* Ap = ws + (dir == 0 ? OFF_APACK_S : OFF_APACK_T);
    const char* Bp = ws + (dir == 0 ? OFF_BPACK_T : OFF_BPACK_S);

    // 2 row-tiles of 32 rows each
    V16 av0, av1;
    av0.i = *(const int4*)(Ap + (size_t)(b * NPTS + stripe * 64 + l31) * 32 + half * 16);
    av1.i = *(const int4*)(Ap + (size_t)(b * NPTS + stripe * 64 + 32 + l31) * 32 + half * 16);

    floatx16 rmin0, rmin1, zero;
#pragma unroll
    for (int r = 0; r < 16; r++) { rmin0[r] = 3.0e38f; rmin1[r] = 3.0e38f; zero[r] = 0.0f; }

    const int ct0 = wave * 32;            // 32 col-tiles (of 32 pts) per wave
    const char* bbase = Bp + (size_t)(b * NPTS + ct0 * 32 + l31) * 32 + half * 16;

    // depth-4 register prefetch ring over 32 tiles, 1024 B apart; wrap &31
    V16 t0, t1, t2, t3;
    t0.i = *(const int4*)(bbase);
    t1.i = *(const int4*)(bbase + 1024);
    t2.i = *(const int4*)(bbase + 2048);
    t3.i = *(const int4*)(bbase + 3072);

#pragma unroll
    for (int i = 0; i < 32; i += 4) {
        V16 n0, n1, n2, n3;
        n0.i = *(const int4*)(bbase + (size_t)((i + 4) & 31) * 1024);
        n1.i = *(const int4*)(bbase + (size_t)((i + 5) & 31) * 1024);
        n2.i = *(const int4*)(bbase + (size_t)((i + 6) & 31) * 1024);
        n3.i = *(const int4*)(bbase + (size_t)((i + 7) & 31) * 1024);
#pragma unroll
        for (int u = 0; u < 4; u++) {
            const bf16x8 bf = (u == 0 ? t0.h : u == 1 ? t1.h : u == 2 ? t2.h : t3.h);
            const floatx16 d0 =
                __builtin_amdgcn_mfma_f32_32x32x16_bf16(av0.h, bf, zero, 0, 0, 0);
            const floatx16 d1 =
                __builtin_amdgcn_mfma_f32_32x32x16_bf16(av1.h, bf, zero, 0, 0, 0);
#pragma unroll
            for (int r = 0; r < 16; r++) {
                rmin0[r] = fminf(rmin0[r], d0[r]);
                rmin1[r] = fminf(rmin1[r], d1[r]);
            }
        }
        t0 = n0; t1 = n1; t2 = n2; t3 = n3;
    }

    // ---- butterfly min over the 32 columns (within each half) ----
#pragma unroll
    for (int off = 1; off < 32; off <<= 1) {
#pragma unroll
        for (int r = 0; r < 16; r++) {
            rmin0[r] = fminf(rmin0[r], __shfl_xor(rmin0[r], off, 64));
            rmin1[r] = fminf(rmin1[r], __shfl_xor(rmin1[r], off, 64));
        }
    }
    // half-leader (l31==0: lanes 0, 32) holds rows (r&3)+8*(r>>2)+4*half
    __shared__ float sRow[4][64];
    if (l31 == 0) {
#pragma unroll
        for (int r = 0; r < 16; r++) {
            const int row = (r & 3) + 8 * (r >> 2) + 4 * half;
            sRow[wave][row]      = rmin0[r];
            sRow[wave][32 + row] = rmin1[r];
        }
    }
    __syncthreads();
    if (tid < 64) {
        float m = fminf(fminf(sRow[0][tid], sRow[1][tid]),
                        fminf(sRow[2][tid], sRow[3][tid]));
        m = fmaxf(m, 0.0f);               // D = P exactly; no halving
        float g = m / (m + 1.0f);         // GM, MU=1
#pragma unroll
        for (int off = 1; off < 64; off <<= 1)
            g += __shfl_xor(g, off, 64);
        if (tid == 0)
            ((float*)(ws + OFF_BSUM))[blk] = g;   // plain store
    }
}

// ---------------- Kernel 3: single-block finish ----------------
__global__ __launch_bounds__(256)
void finish_kernel(const char* __restrict__ ws, float* __restrict__ out) {
    const float* bsum = (const float*)(ws + OFF_BSUM);
    const int tid = threadIdx.x;
    float g = bsum[tid] + bsum[tid + 256] + bsum[tid + 512] + bsum[tid + 768];
#pragma unroll
    for (int off = 1; off < 64; off <<= 1)
        g += __shfl_xor(g, off, 64);
    __shared__ float sp[4];
    if ((tid & 63) == 0) sp[tid >> 6] = g;
    __syncthreads();
    if (tid == 0)
        out[0] = (sp[0] + sp[1] + sp[2] + sp[3]) * (1.0f / (NB * NPTS));
}

extern "C" void kernel_launch(void* const* d_in, const int* in_sizes, int n_in,
                              void* d_out, int out_size, void* d_ws, size_t ws_size,
                              hipStream_t stream) {
    const float* srcs = (const float*)d_in[0];
    const float* tgts = (const float*)d_in[1];
    float* out = (float*)d_out;
    char* ws = (char*)d_ws;

    transform_kernel<<<dim3(256), dim3(256), 0, stream>>>(srcs, tgts, ws);
    chamfer_kernel<<<dim3(1024), dim3(256), 0, stream>>>(ws);
    finish_kernel<<<dim3(1), dim3(256), 0, stream>>>(ws, out);
}

// Round 16
// 74.790 us; speedup vs baseline: 1.0242x; 1.0242x over previous
//
#include <hip/hip_runtime.h>

// GMLoss: bidirectional chamfer min + Geman-McClure penalty (MU=1).
// srcs, tgts: [B=8, D=3, N=4096] fp32. Output: scalar fp32.
//
// R16 = R14 (74.3us best: 16x16x32 + K-replication, 64 rows/block, 256thr)
// + two stall fixes:
//  1. __launch_bounds__(256,4): hard cap 128 VGPR -> guaranteed 4 waves/
//     SIMD. At (256,2) the allocator may exceed 128 VGPR and silently
//     halve occupancy to 2 waves/SIMD (R14 never validated VGPR count).
//     Live set ~108 fits under 128; spill signal = WRITE_SIZE in MB.
//  2. Depth-8 prefetch ring (was 4): lead 8 tiles x ~48 cyc = ~380 cyc >=
//     L2 hit latency (~200-500 cyc, m125/m126). Depth-4's ~190 cyc lead
//     arrived late every iteration.
//
// Kept (absmax 0.0 since R6): K=13 hi/lo pack, K-replication (quads 2,3
// re-read bytes 0..31 -> D=2P, halve after min), plain stores + tiny finish
// (NO fences/hot atomics - R7/R9), XCD swizzle group=blk&15.
//   A k: [-2sh(3), -2sl(3), -2sh(3), s2h, s2l, 1, 1, 0,0,0]
//   B k: [ th(3),   th(3),   tl(3),  1, 1, t2h, t2l, 0,0,0]
//   dot = |s|^2+|t|^2-2s.t  (drops sl.tl ~1e-5 << 1.26e-3 threshold).
// 16x16x32 layouts (m89/m91): A[m=lane&15][k=(lane>>4)*8+j], B same
// (n=lane&15); D: col=lane&15, row=(lane>>4)*4+reg.

#define NPTS 4096
#define NB   8

typedef __attribute__((ext_vector_type(8))) short bf16x8;
typedef __attribute__((ext_vector_type(4))) float floatx4;

// ws layout: Apack[srcs], Apack[tgts], Bpack[srcs], Bpack[tgts], bsum[1024]
#define OFF_APACK_S 0u
#define OFF_APACK_T (1u << 20)
#define OFF_BPACK_S (2u << 20)
#define OFF_BPACK_T (3u << 20)
#define OFF_BSUM    (4u << 20)

union V16 { int4 i; bf16x8 h; };

__device__ __forceinline__ unsigned short f2bf(float f) {
    unsigned u = __float_as_uint(f);
    u += 0x7FFFu + ((u >> 16) & 1u);       // RNE
    return (unsigned short)(u >> 16);
}
__device__ __forceinline__ float bf2f(unsigned short h) {
    return __uint_as_float(((unsigned)h) << 16);
}
__device__ __forceinline__ int pk(unsigned short lo, unsigned short hi) {
    return (int)((unsigned)lo | ((unsigned)hi << 16));
}

// ---------------- Kernel 1: pack A-style + B-style, 1 point/thread --------
__device__ __forceinline__ void pack_point(const float* __restrict__ cloud,
                                           int b, int j, int gid,
                                           char* __restrict__ apack,
                                           char* __restrict__ bpack) {
    const unsigned short ONE = 0x3F80;
    const float* p = cloud + b * 3 * NPTS;
    const float x = p[j], y = p[NPTS + j], z = p[2 * NPTS + j];
    const unsigned short hx = f2bf(x), hy = f2bf(y), hz = f2bf(z);
    const unsigned short lx = f2bf(x - bf2f(hx));
    const unsigned short ly = f2bf(y - bf2f(hy));
    const unsigned short lz = f2bf(z - bf2f(hz));
    const unsigned short a0 = f2bf(-2.0f * bf2f(hx));
    const unsigned short a1 = f2bf(-2.0f * bf2f(hy));
    const unsigned short a2 = f2bf(-2.0f * bf2f(hz));
    const unsigned short m0 = f2bf(-2.0f * (x - bf2f(hx)));
    const unsigned short m1 = f2bf(-2.0f * (y - bf2f(hy)));
    const unsigned short m2 = f2bf(-2.0f * (z - bf2f(hz)));
    const float n2 = fmaf(z, z, fmaf(y, y, x * x));
    const unsigned short n2h = f2bf(n2);
    const unsigned short n2l = f2bf(n2 - bf2f(n2h));

    int4* Ap = (int4*)(apack + (size_t)gid * 32);
    Ap[0] = make_int4(pk(a0, a1), pk(a2, m0), pk(m1, m2), pk(a0, a1));
    Ap[1] = make_int4(pk(a2, n2h), pk(n2l, ONE), pk(ONE, 0), 0);

    int4* Bp = (int4*)(bpack + (size_t)gid * 32);
    Bp[0] = make_int4(pk(hx, hy), pk(hz, hx), pk(hy, hz), pk(lx, ly));
    Bp[1] = make_int4(pk(lz, ONE), pk(ONE, n2h), pk(n2l, 0), 0);
}

__global__ __launch_bounds__(256)
void transform_kernel(const float* __restrict__ srcs,
                      const float* __restrict__ tgts,
                      char* __restrict__ ws) {
    const int gid = blockIdx.x * 256 + threadIdx.x;   // 0..65535
    const int dir = gid >> 15;
    const int rem = gid & 32767;                      // b*4096 + j
    const int b = rem >> 12, j = rem & 4095;
    if (dir == 0)
        pack_point(srcs, b, j, rem, ws + OFF_APACK_S, ws + OFF_BPACK_S);
    else
        pack_point(tgts, b, j, rem, ws + OFF_APACK_T, ws + OFF_BPACK_T);
}

// ---------------- Kernel 2: row-min MFMA chamfer (16x16x32, 64 rows) ------
__global__ __launch_bounds__(256, 4)
void chamfer_kernel(char* __restrict__ ws) {
    const int blk    = blockIdx.x;        // 0..1023
    const int group  = blk & 15;          // XCD-aware swizzle
    const int dir    = group >> 3;
    const int b      = group & 7;
    const int stripe = blk >> 4;          // 0..63, 64 query rows each
    const int tid    = threadIdx.x;
    const int wave   = tid >> 6;          // 0..3
    const int lane   = tid & 63;
    const int l15    = lane & 15;
    const int quad   = lane >> 4;         // k-half = (quad&1)*16 bytes

    const char* Ap = ws + (dir == 0 ? OFF_APACK_S : OFF_APACK_T);
    const char* Bp = ws + (dir == 0 ? OFF_BPACK_T : OFF_BPACK_S);

    // 4 row-tiles of 16 rows; quads 2,3 replicate quads 0,1 -> D = 2P.
    V16 av[4];
#pragma unroll
    for (int rt = 0; rt < 4; rt++)
        av[rt].i = *(const int4*)(Ap +
            (size_t)(b * NPTS + stripe * 64 + rt * 16 + l15) * 32 + (quad & 1) * 16);

    floatx4 rmin[4];
#pragma unroll
    for (int rt = 0; rt < 4; rt++)
        rmin[rt] = (floatx4){3.0e38f, 3.0e38f, 3.0e38f, 3.0e38f};
    const floatx4 zero = {0.0f, 0.0f, 0.0f, 0.0f};

    const int ct0 = wave * 64;            // 64 col-tiles (of 16 pts) per wave
    const char* bbase = Bp + (size_t)(b * NPTS + ct0 * 16 + l15) * 32 + (quad & 1) * 16;

    // depth-8 register prefetch ring over 64 tiles, 512 B apart; wrap &63
    V16 t[8];
#pragma unroll
    for (int k = 0; k < 8; k++)
        t[k].i = *(const int4*)(bbase + (size_t)k * 512);

#pragma unroll
    for (int i = 0; i < 64; i += 8) {
        V16 n[8];
#pragma unroll
        for (int k = 0; k < 8; k++)
            n[k].i = *(const int4*)(bbase + (size_t)((i + 8 + k) & 63) * 512);
#pragma unroll
        for (int u = 0; u < 8; u++) {
            const bf16x8 bf = t[u].h;
#pragma unroll
            for (int rt = 0; rt < 4; rt++) {
                const floatx4 d =
                    __builtin_amdgcn_mfma_f32_16x16x32_bf16(av[rt].h, bf, zero, 0, 0, 0);
#pragma unroll
                for (int r = 0; r < 4; r++)
                    rmin[rt][r] = fminf(rmin[rt][r], d[r]);
            }
        }
#pragma unroll
        for (int k = 0; k < 8; k++) t[k] = n[k];
    }

    // ---- butterfly min over the 16 col-lanes ----
#pragma unroll
    for (int off = 1; off < 16; off <<= 1) {
#pragma unroll
        for (int rt = 0; rt < 4; rt++)
#pragma unroll
            for (int r = 0; r < 4; r++)
                rmin[rt][r] = fminf(rmin[rt][r], __shfl_xor(rmin[rt][r], off, 64));
    }
    // quad leader holds rows rt*16 + quad*4 + r
    __shared__ float sRow[4][64];
    if (l15 == 0) {
#pragma unroll
        for (int rt = 0; rt < 4; rt++)
#pragma unroll
            for (int r = 0; r < 4; r++)
                sRow[wave][rt * 16 + quad * 4 + r] = rmin[rt][r];
    }
    __syncthreads();
    if (tid < 64) {
        float m = fminf(fminf(sRow[0][tid], sRow[1][tid]),
                        fminf(sRow[2][tid], sRow[3][tid]));
        m = fmaxf(m * 0.5f, 0.0f);        // undo K-replication doubling
        float g = m / (m + 1.0f);         // GM, MU=1
#pragma unroll
        for (int off = 1; off < 64; off <<= 1)
            g += __shfl_xor(g, off, 64);
        if (tid == 0)
            ((float*)(ws + OFF_BSUM))[blk] = g;   // plain store
    }
}

// ---------------- Kernel 3: single-block finish ----------------
__global__ __launch_bounds__(256)
void finish_kernel(const char* __restrict__ ws, float* __restrict__ out) {
    const float* bsum = (const float*)(ws + OFF_BSUM);
    const int tid = threadIdx.x;
    float g = bsum[tid] + bsum[tid + 256] + bsum[tid + 512] + bsum[tid + 768];
#pragma unroll
    for (int off = 1; off < 64; off <<= 1)
        g += __shfl_xor(g, off, 64);
    __shared__ float sp[4];
    if ((tid & 63) == 0) sp[tid >> 6] = g;
    __syncthreads();
    if (tid == 0)
        out[0] = (sp[0] + sp[1] + sp[2] + sp[3]) * (1.0f / (NB * NPTS));
}

extern "C" void kernel_launch(void* const* d_in, const int* in_sizes, int n_in,
                              void* d_out, int out_size, void* d_ws, size_t ws_size,
                              hipStream_t stream) {
    const float* srcs = (const float*)d_in[0];
    const float* tgts = (const float*)d_in[1];
    float* out = (float*)d_out;
    char* ws = (char*)d_ws;

    transform_kernel<<<dim3(256), dim3(256), 0, stream>>>(srcs, tgts, ws);
    chamfer_kernel<<<dim3(1024), dim3(256), 0, stream>>>(ws);
    finish_kernel<<<dim3(1), dim3(256), 0, stream>>>(ws, out);
}